// Round 1
// baseline (120.278 us; speedup 1.0000x reference)
//
#include <hip/hip_runtime.h>

// Problem constants (from reference)
#define S0d   256
#define S1d   256
#define BONDd 32
#define BATCHd 2048
#define UNITSd 65536        // S0 * S1
#define UCHUNK 1024         // units per block (256 threads x float4)
#define BCHUNK 64           // batches per block

// ---------------------------------------------------------------------------
// Kernel A: G_j[a*256+c] = sum_p (core1[0,a,p]+core1[1,a,p]) * core2[j,c,p]
// G layout in d_ws: G0[65536] then G1[65536]
// ---------------------------------------------------------------------------
__global__ __launch_bounds__(256) void precompute_G(
    const float* __restrict__ core1, const float* __restrict__ core2,
    float* __restrict__ G) {
  const int u = blockIdx.x * 256 + threadIdx.x;   // 0..65535
  const int a = u >> 8;
  const int c = u & 255;
  const float4* c10 = (const float4*)(core1 + a * BONDd);                 // core1[0,a,:]
  const float4* c11 = (const float4*)(core1 + S0d * BONDd + a * BONDd);   // core1[1,a,:]
  const float4* r0  = (const float4*)(core2 + c * BONDd);                 // core2[0,c,:]
  const float4* r1  = (const float4*)(core2 + S1d * BONDd + c * BONDd);   // core2[1,c,:]
  float acc0 = 0.f, acc1 = 0.f;
#pragma unroll
  for (int q = 0; q < BONDd / 4; ++q) {
    float4 x = c10[q], y = c11[q];
    float sx = x.x + y.x, sy = x.y + y.y, sz = x.z + y.z, sw = x.w + y.w;
    float4 v0 = r0[q], v1 = r1[q];
    acc0 = fmaf(sx, v0.x, fmaf(sy, v0.y, fmaf(sz, v0.z, fmaf(sw, v0.w, acc0))));
    acc1 = fmaf(sx, v1.x, fmaf(sy, v1.y, fmaf(sz, v1.z, fmaf(sw, v1.w, acc1))));
  }
  G[u] = acc0;
  G[UNITSd + u] = acc1;
}

// ---------------------------------------------------------------------------
// Kernel B: out[b,u] = relu(x0[b]*G0[u] + x1[b]*G1[u] + bias[u])
// Each thread holds G0/G1/bias (float4) in registers, loops over BCHUNK b's.
// ---------------------------------------------------------------------------
__global__ __launch_bounds__(256) void td_main(
    const float* __restrict__ inputs, const float* __restrict__ G,
    const float* __restrict__ bias, float* __restrict__ out) {
  const int u = blockIdx.x * UCHUNK + threadIdx.x * 4;
  const float4 g0 = *(const float4*)(G + u);
  const float4 g1 = *(const float4*)(G + UNITSd + u);
  const float4 bs = *(const float4*)(bias + u);
  const int b0 = blockIdx.y * BCHUNK;
  float* outp = out + (size_t)b0 * UNITSd + u;
#pragma unroll 4
  for (int k = 0; k < BCHUNK; ++k) {
    const float2 x = *(const float2*)(inputs + (b0 + k) * 2);
    float4 r;
    r.x = fmaxf(fmaf(x.y, g1.x, fmaf(x.x, g0.x, bs.x)), 0.f);
    r.y = fmaxf(fmaf(x.y, g1.y, fmaf(x.x, g0.y, bs.y)), 0.f);
    r.z = fmaxf(fmaf(x.y, g1.z, fmaf(x.x, g0.z, bs.z)), 0.f);
    r.w = fmaxf(fmaf(x.y, g1.w, fmaf(x.x, g0.w, bs.w)), 0.f);
    *(float4*)outp = r;
    outp += UNITSd;
  }
}

// ---------------------------------------------------------------------------
// Fallback (only if ws_size < 512 KiB): recompute this thread's G in prologue
// ---------------------------------------------------------------------------
__global__ __launch_bounds__(256) void td_fused(
    const float* __restrict__ inputs, const float* __restrict__ core1,
    const float* __restrict__ core2, const float* __restrict__ bias,
    float* __restrict__ out) {
  const int u = blockIdx.x * UCHUNK + threadIdx.x * 4;
  const int a = u >> 8;
  const int c = u & 255;   // c..c+3 all within same a (256 % 4 == 0)
  float s[BONDd];
#pragma unroll
  for (int p = 0; p < BONDd; ++p)
    s[p] = core1[a * BONDd + p] + core1[S0d * BONDd + a * BONDd + p];
  float g0[4], g1[4];
#pragma unroll
  for (int cc = 0; cc < 4; ++cc) {
    float a0 = 0.f, a1 = 0.f;
#pragma unroll
    for (int p = 0; p < BONDd; ++p) {
      a0 = fmaf(s[p], core2[(c + cc) * BONDd + p], a0);
      a1 = fmaf(s[p], core2[S1d * BONDd + (c + cc) * BONDd + p], a1);
    }
    g0[cc] = a0; g1[cc] = a1;
  }
  const float4 bs = *(const float4*)(bias + u);
  const int b0 = blockIdx.y * BCHUNK;
  float* outp = out + (size_t)b0 * UNITSd + u;
#pragma unroll 4
  for (int k = 0; k < BCHUNK; ++k) {
    const float2 x = *(const float2*)(inputs + (b0 + k) * 2);
    float4 r;
    r.x = fmaxf(fmaf(x.y, g1[0], fmaf(x.x, g0[0], bs.x)), 0.f);
    r.y = fmaxf(fmaf(x.y, g1[1], fmaf(x.x, g0[1], bs.y)), 0.f);
    r.z = fmaxf(fmaf(x.y, g1[2], fmaf(x.x, g0[2], bs.z)), 0.f);
    r.w = fmaxf(fmaf(x.y, g1[3], fmaf(x.x, g0[3], bs.w)), 0.f);
    *(float4*)outp = r;
    outp += UNITSd;
  }
}

extern "C" void kernel_launch(void* const* d_in, const int* in_sizes, int n_in,
                              void* d_out, int out_size, void* d_ws, size_t ws_size,
                              hipStream_t stream) {
  const float* inputs = (const float*)d_in[0];  // (2048, 2)
  const float* core1  = (const float*)d_in[1];  // (2, 256, 32)
  const float* core2  = (const float*)d_in[2];  // (2, 256, 32)
  const float* bias   = (const float*)d_in[3];  // (256, 256)
  float* out = (float*)d_out;                   // (2048, 65536)

  const size_t g_bytes = (size_t)2 * UNITSd * sizeof(float);
  if (ws_size >= g_bytes) {
    float* G = (float*)d_ws;
    precompute_G<<<UNITSd / 256, 256, 0, stream>>>(core1, core2, G);
    td_main<<<dim3(UNITSd / UCHUNK, BATCHd / BCHUNK), 256, 0, stream>>>(
        inputs, G, bias, out);
  } else {
    td_fused<<<dim3(UNITSd / UCHUNK, BATCHd / BCHUNK), 256, 0, stream>>>(
        inputs, core1, core2, bias, out);
  }
}

// Round 3
// 111.114 us; speedup vs baseline: 1.0825x; 1.0825x over previous
//
#include <hip/hip_runtime.h>

// Problem constants (from reference)
#define S0d   256
#define S1d   256
#define BONDd 32
#define BATCHd 2048
#define UNITSd 65536        // S0 * S1

typedef float f32x4 __attribute__((ext_vector_type(4)));
typedef float f32x2 __attribute__((ext_vector_type(2)));

// ---------------------------------------------------------------------------
// Kernel A: G_j[a*256+c] = sum_p (core1[0,a,p]+core1[1,a,p]) * core2[j,c,p]
// G layout in d_ws: G0[65536] then G1[65536]
// ---------------------------------------------------------------------------
__global__ __launch_bounds__(256) void precompute_G(
    const float* __restrict__ core1, const float* __restrict__ core2,
    float* __restrict__ G) {
  const int u = blockIdx.x * 256 + threadIdx.x;   // 0..65535
  const int a = u >> 8;
  const int c = u & 255;
  const f32x4* c10 = (const f32x4*)(core1 + a * BONDd);                 // core1[0,a,:]
  const f32x4* c11 = (const f32x4*)(core1 + S0d * BONDd + a * BONDd);   // core1[1,a,:]
  const f32x4* r0  = (const f32x4*)(core2 + c * BONDd);                 // core2[0,c,:]
  const f32x4* r1  = (const f32x4*)(core2 + S1d * BONDd + c * BONDd);   // core2[1,c,:]
  float acc0 = 0.f, acc1 = 0.f;
#pragma unroll
  for (int q = 0; q < BONDd / 4; ++q) {
    f32x4 x = c10[q], y = c11[q];
    f32x4 s = x + y;
    f32x4 v0 = r0[q], v1 = r1[q];
    acc0 = fmaf(s.x, v0.x, fmaf(s.y, v0.y, fmaf(s.z, v0.z, fmaf(s.w, v0.w, acc0))));
    acc1 = fmaf(s.x, v1.x, fmaf(s.y, v1.y, fmaf(s.z, v1.z, fmaf(s.w, v1.w, acc1))));
  }
  G[u] = acc0;
  G[UNITSd + u] = acc1;
}

// ---------------------------------------------------------------------------
// Kernel B (row-linear): block b writes out[b, :] (256 KiB) sequentially.
// G0/G1/bias stream from L2 (768 KiB hot set per XCD); output bypasses L2
// via nontemporal stores so the hot set stays resident.
// ---------------------------------------------------------------------------
__global__ __launch_bounds__(256) void td_row(
    const float* __restrict__ inputs, const float* __restrict__ G,
    const float* __restrict__ bias, float* __restrict__ out) {
  const int b = blockIdx.x;
  const f32x2 x = *(const f32x2*)(inputs + b * 2);   // uniform per block
  float* outp = out + (size_t)b * UNITSd;
  const int base = threadIdx.x * 4;
#pragma unroll 4
  for (int it = 0; it < UNITSd / 1024; ++it) {
    const int u = it * 1024 + base;
    const f32x4 g0 = *(const f32x4*)(G + u);
    const f32x4 g1 = *(const f32x4*)(G + UNITSd + u);
    const f32x4 bs = *(const f32x4*)(bias + u);
    f32x4 r;
    r.x = fmaxf(fmaf(x.y, g1.x, fmaf(x.x, g0.x, bs.x)), 0.f);
    r.y = fmaxf(fmaf(x.y, g1.y, fmaf(x.x, g0.y, bs.y)), 0.f);
    r.z = fmaxf(fmaf(x.y, g1.z, fmaf(x.x, g0.z, bs.z)), 0.f);
    r.w = fmaxf(fmaf(x.y, g1.w, fmaf(x.x, g0.w, bs.w)), 0.f);
    __builtin_nontemporal_store(r, (f32x4*)(outp + u));
  }
}

// ---------------------------------------------------------------------------
// Fallback (only if ws_size < 512 KiB): recompute this thread's G in prologue
// ---------------------------------------------------------------------------
__global__ __launch_bounds__(256) void td_fused(
    const float* __restrict__ inputs, const float* __restrict__ core1,
    const float* __restrict__ core2, const float* __restrict__ bias,
    float* __restrict__ out) {
  const int u = blockIdx.x * 1024 + threadIdx.x * 4;
  const int a = u >> 8;
  const int c = u & 255;   // c..c+3 all within same a (256 % 4 == 0)
  float s[BONDd];
#pragma unroll
  for (int p = 0; p < BONDd; ++p)
    s[p] = core1[a * BONDd + p] + core1[S0d * BONDd + a * BONDd + p];
  float g0[4], g1[4];
#pragma unroll
  for (int cc = 0; cc < 4; ++cc) {
    float a0 = 0.f, a1 = 0.f;
#pragma unroll
    for (int p = 0; p < BONDd; ++p) {
      a0 = fmaf(s[p], core2[(c + cc) * BONDd + p], a0);
      a1 = fmaf(s[p], core2[S1d * BONDd + (c + cc) * BONDd + p], a1);
    }
    g0[cc] = a0; g1[cc] = a1;
  }
  const f32x4 bs = *(const f32x4*)(bias + u);
  const int b0 = blockIdx.y * 64;
  float* outp = out + (size_t)b0 * UNITSd + u;
#pragma unroll 4
  for (int k = 0; k < 64; ++k) {
    const f32x2 x = *(const f32x2*)(inputs + (b0 + k) * 2);
    f32x4 r;
    r.x = fmaxf(fmaf(x.y, g1[0], fmaf(x.x, g0[0], bs.x)), 0.f);
    r.y = fmaxf(fmaf(x.y, g1[1], fmaf(x.x, g0[1], bs.y)), 0.f);
    r.z = fmaxf(fmaf(x.y, g1[2], fmaf(x.x, g0[2], bs.z)), 0.f);
    r.w = fmaxf(fmaf(x.y, g1[3], fmaf(x.x, g0[3], bs.w)), 0.f);
    *(f32x4*)outp = r;
    outp += UNITSd;
  }
}

extern "C" void kernel_launch(void* const* d_in, const int* in_sizes, int n_in,
                              void* d_out, int out_size, void* d_ws, size_t ws_size,
                              hipStream_t stream) {
  const float* inputs = (const float*)d_in[0];  // (2048, 2)
  const float* core1  = (const float*)d_in[1];  // (2, 256, 32)
  const float* core2  = (const float*)d_in[2];  // (2, 256, 32)
  const float* bias   = (const float*)d_in[3];  // (256, 256)
  float* out = (float*)d_out;                   // (2048, 65536)

  const size_t g_bytes = (size_t)2 * UNITSd * sizeof(float);
  if (ws_size >= g_bytes) {
    float* G = (float*)d_ws;
    precompute_G<<<UNITSd / 256, 256, 0, stream>>>(core1, core2, G);
    td_row<<<BATCHd, 256, 0, stream>>>(inputs, G, bias, out);
  } else {
    td_fused<<<dim3(UNITSd / 1024, BATCHd / 64), 256, 0, stream>>>(
        inputs, core1, core2, bias, out);
  }
}